// Round 10
// baseline (100.884 us; speedup 1.0000x reference)
//
#include <hip/hip_runtime.h>
#include <hip/hip_bf16.h>

// GATLayer, scalar attention => uniform 1/deg over DISTINCT neighbors.
//   out[n, h*D+d] = sum_k W[h,d,k] * agg_x[n,k]
//   agg_x[n,:]    = mean_{j in distinct nbr(n)} x[j,:]  (mean over all N if deg==0)
// 2 launches (@~3.5us/node overhead):
//   scan_agg_k : per-block edge scan -> private LDS bitmask -> gather-mean
//   gemm_k     : R8 reg-staged MFMA GEMM, W fp32->bf16 converted in staging

constexpr int NN = 4096;          // nodes
constexpr int DD = 256;           // channels
constexpr int EE = 131072;        // edges
constexpr int MW = NN / 32;       // 128 mask words per row
constexpr int NOUT = 2048;        // H*D
constexpr int RPB = 16;           // rows per scan block
constexpr int NBA = NN / RPB;     // 256 blocks
constexpr int LCAP = 128;         // neighbor cap (deg ~ Poisson(32), max ~70)
constexpr int BK = 32;
constexpr int PADK = 40;          // 80B LDS row stride (proven R8)

typedef __attribute__((ext_vector_type(4))) float f32x4;
typedef __attribute__((ext_vector_type(8))) short s16x8;

__device__ inline short f2bf(float f) {
    __hip_bfloat16 h = __float2bfloat16(f);
    return *reinterpret_cast<short*>(&h);
}
__device__ inline s16x8 cvt8(const float4& a, const float4& b) {
    s16x8 o;
    o[0] = f2bf(a.x); o[1] = f2bf(a.y); o[2] = f2bf(a.z); o[3] = f2bf(a.w);
    o[4] = f2bf(b.x); o[5] = f2bf(b.y); o[6] = f2bf(b.z); o[7] = f2bf(b.w);
    return o;
}

// ---- launch 1: edge scan -> LDS bitmask -> compact -> gather-mean -> bf16 ----
// Block owns 16 rows. u-array (512 KB, int32) is L2-broadcast to all blocks.
__global__ __launch_bounds__(512) void scan_agg_k(
        const float* __restrict__ x, const int* __restrict__ eu,
        const int* __restrict__ ev, short* __restrict__ aggb) {
    __shared__ unsigned int bm[RPB][MW];     // 8 KB private bitmask
    __shared__ int nbr[RPB][LCAP];           // 8 KB
    __shared__ int cnt[RPB];
    const int t = threadIdx.x;
    const int row0 = blockIdx.x * RPB;

    for (int i = t; i < RPB * MW; i += 512) ((unsigned int*)bm)[i] = 0u;
    if (t < RPB) cnt[t] = 0;
    __syncthreads();

    // scan: 256 edges/thread, coalesced u reads; v fetched only on range hit
    for (int e = t; e < EE; e += 512) {
        int u = eu[e];
        if ((unsigned)(u - row0) < (unsigned)RPB) {
            int v = ev[e];
            atomicOr(&bm[u - row0][v >> 5], 1u << (v & 31));
        }
    }
    __syncthreads();

    const int wv = t >> 6;                   // 8 waves, 2 rows each
    const int lane = t & 63;
#pragma unroll
    for (int rr = 0; rr < 2; ++rr) {         // compact: 64 lanes x 2 words
        const int r = wv * 2 + rr;
#pragma unroll
        for (int j = 0; j < 2; ++j) {
            unsigned int m = bm[r][lane * 2 + j];
            while (m) {
                int b = __ffs(m) - 1;
                m &= m - 1;
                int idx = atomicAdd(&cnt[r], 1);
                if (idx < LCAP) nbr[r][idx] = (lane * 2 + j) * 32 + b;
            }
        }
    }
    __syncthreads();

    const int c4 = lane << 2;                // 4 ch/lane -> 64 lanes = full row
#pragma unroll
    for (int rr = 0; rr < 2; ++rr) {
        const int r = wv * 2 + rr;
        const int deg = min(cnt[r], LCAP);
        float4 acc = make_float4(0.f, 0.f, 0.f, 0.f);
        for (int q0 = 0; q0 < deg; q0 += 8) {        // 8 loads in flight
            int nn[8];
            float4 v[8];
#pragma unroll
            for (int j = 0; j < 8; ++j)
                nn[j] = nbr[r][(q0 + j < deg) ? q0 + j : q0];
#pragma unroll
            for (int j = 0; j < 8; ++j)
                v[j] = *reinterpret_cast<const float4*>(&x[(size_t)nn[j] * DD + c4]);
#pragma unroll
            for (int j = 0; j < 8; ++j)
                if (q0 + j < deg) {
                    acc.x += v[j].x; acc.y += v[j].y;
                    acc.z += v[j].z; acc.w += v[j].w;
                }
        }
        float inv;
        if (deg > 0) {
            inv = 1.f / (float)deg;
        } else {                 // exact fallback: mean over all N (never expected)
            acc = make_float4(0.f, 0.f, 0.f, 0.f);
            for (int n = 0; n < NN; ++n) {
                float4 v = *reinterpret_cast<const float4*>(&x[(size_t)n * DD + c4]);
                acc.x += v.x; acc.y += v.y; acc.z += v.z; acc.w += v.w;
            }
            inv = 1.f / (float)NN;
        }
        short4 o;
        o.x = f2bf(acc.x * inv); o.y = f2bf(acc.y * inv);
        o.z = f2bf(acc.z * inv); o.w = f2bf(acc.w * inv);
        *reinterpret_cast<short4*>(&aggb[(size_t)(row0 + r) * DD + c4]) = o;
    }
}

// ---- launch 2: MFMA GEMM  C[4096][2048] = aggb[4096][256] * W[2048][256]^T ----
// R8 structure: 128x128 tile, BK=32, padded double-buffered LDS, reg-staged
// (write-early, load-2-ahead), one barrier per K-step. W converted fp32->bf16
// during staging. 4 waves (2x2), 64x64 per wave.
__global__ __launch_bounds__(256, 2) void gemm_k(
        const short* __restrict__ A, const float* __restrict__ Bf,
        float* __restrict__ C) {
    __shared__ short As[2][128][PADK];   // 2 x 10 KB
    __shared__ short Bs[2][128][PADK];   // 2 x 10 KB
    const int t = threadIdx.x;
    const int lane = t & 63;
    const int wv = t >> 6;
    const int wr = wv >> 1, wc = wv & 1;
    const int m0 = blockIdx.y * 128;
    const int n0 = blockIdx.x * 128;
    const int lr = lane & 15;
    const int lk = (lane >> 4) * 8;
    const int srow = t >> 2;             // staging row (and +64)
    const int skc = (t & 3) * 8;         // staging k-col (8 elements)

    f32x4 acc[4][4] = {};
    s16x8 ra0, ra1;
    float4 rb00, rb01, rb10, rb11;

#define LOADG(k0)                                                                        \
    {                                                                                    \
        ra0 = *reinterpret_cast<const s16x8*>(&A[(size_t)(m0 + srow) * DD + (k0) + skc]);       \
        ra1 = *reinterpret_cast<const s16x8*>(&A[(size_t)(m0 + 64 + srow) * DD + (k0) + skc]);  \
        rb00 = *reinterpret_cast<const float4*>(&Bf[(size_t)(n0 + srow) * DD + (k0) + skc]);    \
        rb01 = *reinterpret_cast<const float4*>(&Bf[(size_t)(n0 + srow) * DD + (k0) + skc + 4]);\
        rb10 = *reinterpret_cast<const float4*>(&Bf[(size_t)(n0 + 64 + srow) * DD + (k0) + skc]);    \
        rb11 = *reinterpret_cast<const float4*>(&Bf[(size_t)(n0 + 64 + srow) * DD + (k0) + skc + 4]);\
    }
#define WRITEL(buf)                                                         \
    {                                                                       \
        *reinterpret_cast<s16x8*>(&As[buf][srow][skc]) = ra0;               \
        *reinterpret_cast<s16x8*>(&As[buf][srow + 64][skc]) = ra1;          \
        *reinterpret_cast<s16x8*>(&Bs[buf][srow][skc]) = cvt8(rb00, rb01);  \
        *reinterpret_cast<s16x8*>(&Bs[buf][srow + 64][skc]) = cvt8(rb10, rb11); \
    }

    LOADG(0)
    WRITEL(0)
    __syncthreads();
    LOADG(BK)                            // tile 1 in regs

#pragma unroll
    for (int k = 0; k < 8; ++k) {
        const int cur = k & 1;
        if (k < 7) WRITEL(cur ^ 1)       // write tile k+1 (regs loaded an iter ago)
        s16x8 a[4], b[4];
#pragma unroll
        for (int i = 0; i < 4; ++i)
            a[i] = *reinterpret_cast<const s16x8*>(&As[cur][wr * 64 + i * 16 + lr][lk]);
#pragma unroll
        for (int j = 0; j < 4; ++j)
            b[j] = *reinterpret_cast<const s16x8*>(&Bs[cur][wc * 64 + j * 16 + lr][lk]);
        if (k < 6) LOADG((k + 2) * BK)   // issue loads 2 tiles ahead
#pragma unroll
        for (int i = 0; i < 4; ++i)
#pragma unroll
            for (int j = 0; j < 4; ++j)
                acc[i][j] = __builtin_amdgcn_mfma_f32_16x16x32_bf16(
                    a[i], b[j], acc[i][j], 0, 0, 0);
        __syncthreads();                 // all reads of buf[cur] done; writes visible
    }
#undef LOADG
#undef WRITEL

    // C/D layout: col = lane&15, row = (lane>>4)*4 + reg
    const int crow = (lane >> 4) * 4;
    const int ccol = lane & 15;
#pragma unroll
    for (int i = 0; i < 4; ++i)
#pragma unroll
        for (int j = 0; j < 4; ++j)
#pragma unroll
            for (int r = 0; r < 4; ++r)
                C[(size_t)(m0 + wr * 64 + i * 16 + crow + r) * NOUT
                  + n0 + wc * 64 + j * 16 + ccol] = acc[i][j][r];
}

extern "C" void kernel_launch(void* const* d_in, const int* in_sizes, int n_in,
                              void* d_out, int out_size, void* d_ws, size_t ws_size,
                              hipStream_t stream) {
    const float* x  = (const float*)d_in[0];
    const float* lw = (const float*)d_in[1];   // [H][D][D] == [2048][256] row-major
    const int*   ei = (const int*)d_in[4];     // int32 delivery confirmed (R8 passed)
    float* out = (float*)d_out;

    short* aggb = (short*)d_ws;                // 2 MB bf16

    scan_agg_k<<<NBA, 512, 0, stream>>>(x, ei, ei + EE, aggb);

    dim3 ggrid(NOUT / 128, NN / 128);          // (16, 32) = 512 blocks
    gemm_k<<<ggrid, 256, 0, stream>>>(aggb, lw, out);
}

// Round 11
// 54.862 us; speedup vs baseline: 1.8389x; 1.8389x over previous
//
#include <hip/hip_runtime.h>
#include <hip/hip_bf16.h>

// GATLayer, scalar attention => uniform 1/deg over DISTINCT neighbors.
//   out[n, h*D+d] = sum_k W[h,d,k] * agg_x[n,k]
//   agg_x[n,:]    = mean_{j in distinct nbr(n)} x[j,:]  (mean over all N if deg==0)
// 2 launches:
//   scan_agg_k : blockwise edge scan (int4, 8-deep) -> LDS bitmask ->
//                shfl-prefix compaction (no atomics) -> 8-deep gather-mean
//   gemm_k     : reg-staged MFMA GEMM, W fp32->bf16 converted during staging

constexpr int NN = 4096;          // nodes
constexpr int DD = 256;           // channels
constexpr int EE = 131072;        // edges
constexpr int MW = NN / 32;       // 128 mask words per row
constexpr int NOUT = 2048;        // H*D
constexpr int RPB = 16;           // rows per scan block
constexpr int NBA = NN / RPB;     // 256 blocks
constexpr int LCAP = 128;         // neighbor cap (deg ~ Poisson(32), max ~70)
constexpr int BK = 32;
constexpr int PADK = 40;          // 80B LDS row stride (proven R8)

typedef __attribute__((ext_vector_type(4))) float f32x4;
typedef __attribute__((ext_vector_type(8))) short s16x8;

__device__ inline short f2bf(float f) {
    __hip_bfloat16 h = __float2bfloat16(f);
    return *reinterpret_cast<short*>(&h);
}
__device__ inline s16x8 cvt8(const float4& a, const float4& b) {
    s16x8 o;
    o[0] = f2bf(a.x); o[1] = f2bf(a.y); o[2] = f2bf(a.z); o[3] = f2bf(a.w);
    o[4] = f2bf(b.x); o[5] = f2bf(b.y); o[6] = f2bf(b.z); o[7] = f2bf(b.w);
    return o;
}

// ---- launch 1: edge scan -> LDS bitmask -> shfl compaction -> gather-mean ----
__global__ __launch_bounds__(512) void scan_agg_k(
        const float* __restrict__ x, const int* __restrict__ eu,
        const int* __restrict__ ev, short* __restrict__ aggb) {
    __shared__ unsigned int bm[RPB][MW];     // 8 KB private bitmask
    __shared__ int nbr[RPB][LCAP];           // 8 KB
    __shared__ int cnt[RPB];
    const int t = threadIdx.x;
    const int row0 = blockIdx.x * RPB;

    for (int i = t; i < RPB * MW; i += 512) ((unsigned int*)bm)[i] = 0u;
    __syncthreads();

    // scan: 32768 int4 u-loads, 64/thread in 8 rounds of 8-in-flight
    const int4* eu4 = reinterpret_cast<const int4*>(eu);
    for (int r0 = 0; r0 < 8; ++r0) {
        int4 u4[8];
#pragma unroll
        for (int j = 0; j < 8; ++j)
            u4[j] = eu4[t + (r0 * 8 + j) * 512];
#pragma unroll
        for (int j = 0; j < 8; ++j) {
            const int base = (t + (r0 * 8 + j) * 512) * 4;
            const int us[4] = {u4[j].x, u4[j].y, u4[j].z, u4[j].w};
#pragma unroll
            for (int q = 0; q < 4; ++q)
                if ((unsigned)(us[q] - row0) < (unsigned)RPB) {
                    int v = ev[base + q];
                    atomicOr(&bm[us[q] - row0][v >> 5], 1u << (v & 31));
                }
        }
    }
    __syncthreads();

    const int wv = t >> 6;                   // 8 waves, 2 rows each
    const int lane = t & 63;
#pragma unroll
    for (int rr = 0; rr < 2; ++rr) {         // compaction: shfl prefix, no atomics
        const int r = wv * 2 + rr;
        unsigned int w0 = bm[r][lane * 2];
        unsigned int w1 = bm[r][lane * 2 + 1];
        int c = __popc(w0) + __popc(w1);
        int pre = c;
#pragma unroll
        for (int d = 1; d < 64; d <<= 1) {   // inclusive scan over 64 lanes
            int y = __shfl_up(pre, d);
            if (lane >= d) pre += y;
        }
        if (lane == 63) cnt[r] = pre;        // total distinct neighbors
        pre -= c;                            // exclusive prefix
        int idx = pre;
        while (w0) {
            int b = __ffs(w0) - 1; w0 &= w0 - 1;
            if (idx < LCAP) nbr[r][idx] = lane * 64 + b;
            ++idx;
        }
        while (w1) {
            int b = __ffs(w1) - 1; w1 &= w1 - 1;
            if (idx < LCAP) nbr[r][idx] = lane * 64 + 32 + b;
            ++idx;
        }
    }
    __syncthreads();

    const int c4 = lane << 2;                // 4 ch/lane -> 64 lanes = full row
#pragma unroll
    for (int rr = 0; rr < 2; ++rr) {
        const int r = wv * 2 + rr;
        const int deg = min(cnt[r], LCAP);
        float4 acc = make_float4(0.f, 0.f, 0.f, 0.f);
        for (int q0 = 0; q0 < deg; q0 += 8) {        // 8 gathers in flight
            int nn[8];
            float4 v[8];
#pragma unroll
            for (int j = 0; j < 8; ++j)
                nn[j] = nbr[r][(q0 + j < deg) ? q0 + j : q0];
#pragma unroll
            for (int j = 0; j < 8; ++j)
                v[j] = *reinterpret_cast<const float4*>(&x[(size_t)nn[j] * DD + c4]);
#pragma unroll
            for (int j = 0; j < 8; ++j)
                if (q0 + j < deg) {
                    acc.x += v[j].x; acc.y += v[j].y;
                    acc.z += v[j].z; acc.w += v[j].w;
                }
        }
        float inv;
        if (deg > 0) {
            inv = 1.f / (float)deg;
        } else {                 // exact fallback: mean over all N (never expected)
            acc = make_float4(0.f, 0.f, 0.f, 0.f);
            for (int n = 0; n < NN; ++n) {
                float4 v = *reinterpret_cast<const float4*>(&x[(size_t)n * DD + c4]);
                acc.x += v.x; acc.y += v.y; acc.z += v.z; acc.w += v.w;
            }
            inv = 1.f / (float)NN;
        }
        short4 o;
        o.x = f2bf(acc.x * inv); o.y = f2bf(acc.y * inv);
        o.z = f2bf(acc.z * inv); o.w = f2bf(acc.w * inv);
        *reinterpret_cast<short4*>(&aggb[(size_t)(row0 + r) * DD + c4]) = o;
    }
}

// ---- launch 2: MFMA GEMM  C[4096][2048] = aggb[4096][256] * W[2048][256]^T ----
// 128x128 tile, BK=32, padded double-buffered LDS, reg-staged (write-early,
// load-2-ahead), one barrier per K-step. W converted fp32->bf16 in staging.
__global__ __launch_bounds__(256, 2) void gemm_k(
        const short* __restrict__ A, const float* __restrict__ Bf,
        float* __restrict__ C) {
    __shared__ short As[2][128][PADK];   // 2 x 10 KB
    __shared__ short Bs[2][128][PADK];   // 2 x 10 KB
    const int t = threadIdx.x;
    const int lane = t & 63;
    const int wv = t >> 6;
    const int wr = wv >> 1, wc = wv & 1;
    const int m0 = blockIdx.y * 128;
    const int n0 = blockIdx.x * 128;
    const int lr = lane & 15;
    const int lk = (lane >> 4) * 8;
    const int srow = t >> 2;             // staging row (and +64)
    const int skc = (t & 3) * 8;         // staging k-col (8 elements)

    f32x4 acc[4][4] = {};
    s16x8 ra0, ra1;
    float4 rb00, rb01, rb10, rb11;

#define LOADG(k0)                                                                        \
    {                                                                                    \
        ra0 = *reinterpret_cast<const s16x8*>(&A[(size_t)(m0 + srow) * DD + (k0) + skc]);       \
        ra1 = *reinterpret_cast<const s16x8*>(&A[(size_t)(m0 + 64 + srow) * DD + (k0) + skc]);  \
        rb00 = *reinterpret_cast<const float4*>(&Bf[(size_t)(n0 + srow) * DD + (k0) + skc]);    \
        rb01 = *reinterpret_cast<const float4*>(&Bf[(size_t)(n0 + srow) * DD + (k0) + skc + 4]);\
        rb10 = *reinterpret_cast<const float4*>(&Bf[(size_t)(n0 + 64 + srow) * DD + (k0) + skc]);    \
        rb11 = *reinterpret_cast<const float4*>(&Bf[(size_t)(n0 + 64 + srow) * DD + (k0) + skc + 4]);\
    }
#define WRITEL(buf)                                                         \
    {                                                                       \
        *reinterpret_cast<s16x8*>(&As[buf][srow][skc]) = ra0;               \
        *reinterpret_cast<s16x8*>(&As[buf][srow + 64][skc]) = ra1;          \
        *reinterpret_cast<s16x8*>(&Bs[buf][srow][skc]) = cvt8(rb00, rb01);  \
        *reinterpret_cast<s16x8*>(&Bs[buf][srow + 64][skc]) = cvt8(rb10, rb11); \
    }

    LOADG(0)
    WRITEL(0)
    __syncthreads();
    LOADG(BK)                            // tile 1 in regs

#pragma unroll
    for (int k = 0; k < 8; ++k) {
        const int cur = k & 1;
        if (k < 7) WRITEL(cur ^ 1)       // write tile k+1 (regs loaded an iter ago)
        s16x8 a[4], b[4];
#pragma unroll
        for (int i = 0; i < 4; ++i)
            a[i] = *reinterpret_cast<const s16x8*>(&As[cur][wr * 64 + i * 16 + lr][lk]);
#pragma unroll
        for (int j = 0; j < 4; ++j)
            b[j] = *reinterpret_cast<const s16x8*>(&Bs[cur][wc * 64 + j * 16 + lr][lk]);
        if (k < 6) LOADG((k + 2) * BK)   // issue loads 2 tiles ahead
#pragma unroll
        for (int i = 0; i < 4; ++i)
#pragma unroll
            for (int j = 0; j < 4; ++j)
                acc[i][j] = __builtin_amdgcn_mfma_f32_16x16x32_bf16(
                    a[i], b[j], acc[i][j], 0, 0, 0);
        __syncthreads();                 // all reads of buf[cur] done; writes visible
    }
#undef LOADG
#undef WRITEL

    // C/D layout: col = lane&15, row = (lane>>4)*4 + reg
    const int crow = (lane >> 4) * 4;
    const int ccol = lane & 15;
#pragma unroll
    for (int i = 0; i < 4; ++i)
#pragma unroll
        for (int j = 0; j < 4; ++j)
#pragma unroll
            for (int r = 0; r < 4; ++r)
                C[(size_t)(m0 + wr * 64 + i * 16 + crow + r) * NOUT
                  + n0 + wc * 64 + j * 16 + ccol] = acc[i][j][r];
}

extern "C" void kernel_launch(void* const* d_in, const int* in_sizes, int n_in,
                              void* d_out, int out_size, void* d_ws, size_t ws_size,
                              hipStream_t stream) {
    const float* x  = (const float*)d_in[0];
    const float* lw = (const float*)d_in[1];   // [H][D][D] == [2048][256] row-major
    const int*   ei = (const int*)d_in[4];     // int32 delivery (confirmed R8-R10)
    float* out = (float*)d_out;

    short* aggb = (short*)d_ws;                // 2 MB bf16

    scan_agg_k<<<NBA, 512, 0, stream>>>(x, ei, ei + EE, aggb);

    dim3 ggrid(NOUT / 128, NN / 128);          // (16, 32) = 512 blocks
    gemm_k<<<ggrid, 256, 0, stream>>>(aggb, lw, out);
}

// Round 12
// 43.571 us; speedup vs baseline: 2.3154x; 1.2591x over previous
//
#include <hip/hip_runtime.h>
#include <hip/hip_bf16.h>

// GATLayer, scalar attention => uniform 1/deg over DISTINCT neighbors.
//   out[n, h*D+d] = sum_k W[h,d,k] * agg_x[n,k]
//   agg_x[n,:]    = mean_{j in distinct nbr(n)} x[j,:]  (mean over all N if deg==0)
// 2 launches:
//   scan_agg_k : 1024-thr blockwise edge scan (int4, 8-deep) -> LDS bitmask ->
//                shfl-prefix compaction (no atomics) -> 8-deep gather-mean
//   gemm_k     : reg-staged MFMA GEMM, W fp32->bf16 converted during staging

constexpr int NN = 4096;          // nodes
constexpr int DD = 256;           // channels
constexpr int EE = 131072;        // edges
constexpr int MW = NN / 32;       // 128 mask words per row
constexpr int NOUT = 2048;        // H*D
constexpr int RPB = 16;           // rows per scan block (= 16 waves, 1 row/wave)
constexpr int NBA = NN / RPB;     // 256 blocks
constexpr int LCAP = 128;         // neighbor cap (deg ~ Poisson(32), max ~70)
constexpr int BK = 32;
constexpr int PADK = 40;          // 80B LDS row stride (proven R8)

typedef __attribute__((ext_vector_type(4))) float f32x4;
typedef __attribute__((ext_vector_type(8))) short s16x8;

__device__ inline short f2bf(float f) {
    __hip_bfloat16 h = __float2bfloat16(f);
    return *reinterpret_cast<short*>(&h);
}
__device__ inline s16x8 cvt8(const float4& a, const float4& b) {
    s16x8 o;
    o[0] = f2bf(a.x); o[1] = f2bf(a.y); o[2] = f2bf(a.z); o[3] = f2bf(a.w);
    o[4] = f2bf(b.x); o[5] = f2bf(b.y); o[6] = f2bf(b.z); o[7] = f2bf(b.w);
    return o;
}

// ---- launch 1: edge scan -> LDS bitmask -> shfl compaction -> gather-mean ----
__global__ __launch_bounds__(1024) void scan_agg_k(
        const float* __restrict__ x, const int* __restrict__ eu,
        const int* __restrict__ ev, short* __restrict__ aggb) {
    __shared__ unsigned int bm[RPB][MW];     // 8 KB private bitmask
    __shared__ int nbr[RPB][LCAP];           // 8 KB
    __shared__ int cnt[RPB];
    const int t = threadIdx.x;
    const int row0 = blockIdx.x * RPB;

    for (int i = t; i < RPB * MW; i += 1024) ((unsigned int*)bm)[i] = 0u;
    __syncthreads();

    // scan: 32768 int4 u-loads, 32/thread in 4 rounds of 8-in-flight
    const int4* eu4 = reinterpret_cast<const int4*>(eu);
    for (int r0 = 0; r0 < 4; ++r0) {
        int4 u4[8];
#pragma unroll
        for (int j = 0; j < 8; ++j)
            u4[j] = eu4[t + (r0 * 8 + j) * 1024];
#pragma unroll
        for (int j = 0; j < 8; ++j) {
            const int base = (t + (r0 * 8 + j) * 1024) * 4;
            const int us[4] = {u4[j].x, u4[j].y, u4[j].z, u4[j].w};
#pragma unroll
            for (int q = 0; q < 4; ++q)
                if ((unsigned)(us[q] - row0) < (unsigned)RPB) {
                    int v = ev[base + q];
                    atomicOr(&bm[us[q] - row0][v >> 5], 1u << (v & 31));
                }
        }
    }
    __syncthreads();

    const int r = t >> 6;                    // 16 waves, one row per wave
    const int lane = t & 63;
    {                                        // compaction: shfl prefix, no atomics
        unsigned int w0 = bm[r][lane * 2];
        unsigned int w1 = bm[r][lane * 2 + 1];
        int c = __popc(w0) + __popc(w1);
        int pre = c;
#pragma unroll
        for (int d = 1; d < 64; d <<= 1) {   // inclusive scan over 64 lanes
            int y = __shfl_up(pre, d);
            if (lane >= d) pre += y;
        }
        if (lane == 63) cnt[r] = pre;        // total distinct neighbors
        pre -= c;                            // exclusive prefix
        int idx = pre;
        while (w0) {
            int b = __ffs(w0) - 1; w0 &= w0 - 1;
            if (idx < LCAP) nbr[r][idx] = lane * 64 + b;
            ++idx;
        }
        while (w1) {
            int b = __ffs(w1) - 1; w1 &= w1 - 1;
            if (idx < LCAP) nbr[r][idx] = lane * 64 + 32 + b;
            ++idx;
        }
    }
    __syncthreads();

    const int c4 = lane << 2;                // 4 ch/lane -> 64 lanes = full row
    {
        const int deg = min(cnt[r], LCAP);
        float4 acc = make_float4(0.f, 0.f, 0.f, 0.f);
        for (int q0 = 0; q0 < deg; q0 += 8) {        // 8 gathers in flight
            int nn[8];
            float4 v[8];
#pragma unroll
            for (int j = 0; j < 8; ++j)
                nn[j] = nbr[r][(q0 + j < deg) ? q0 + j : q0];
#pragma unroll
            for (int j = 0; j < 8; ++j)
                v[j] = *reinterpret_cast<const float4*>(&x[(size_t)nn[j] * DD + c4]);
#pragma unroll
            for (int j = 0; j < 8; ++j)
                if (q0 + j < deg) {
                    acc.x += v[j].x; acc.y += v[j].y;
                    acc.z += v[j].z; acc.w += v[j].w;
                }
        }
        float inv;
        if (deg > 0) {
            inv = 1.f / (float)deg;
        } else {                 // exact fallback: mean over all N (never expected)
            acc = make_float4(0.f, 0.f, 0.f, 0.f);
            for (int n = 0; n < NN; ++n) {
                float4 v = *reinterpret_cast<const float4*>(&x[(size_t)n * DD + c4]);
                acc.x += v.x; acc.y += v.y; acc.z += v.z; acc.w += v.w;
            }
            inv = 1.f / (float)NN;
        }
        short4 o;
        o.x = f2bf(acc.x * inv); o.y = f2bf(acc.y * inv);
        o.z = f2bf(acc.z * inv); o.w = f2bf(acc.w * inv);
        *reinterpret_cast<short4*>(&aggb[(size_t)(row0 + r) * DD + c4]) = o;
    }
}

// ---- launch 2: MFMA GEMM  C[4096][2048] = aggb[4096][256] * W[2048][256]^T ----
// 128x128 tile, BK=32, padded double-buffered LDS, reg-staged (write-early,
// load-2-ahead), one barrier per K-step. W converted fp32->bf16 in staging.
__global__ __launch_bounds__(256, 2) void gemm_k(
        const short* __restrict__ A, const float* __restrict__ Bf,
        float* __restrict__ C) {
    __shared__ short As[2][128][PADK];   // 2 x 10 KB
    __shared__ short Bs[2][128][PADK];   // 2 x 10 KB
    const int t = threadIdx.x;
    const int lane = t & 63;
    const int wv = t >> 6;
    const int wr = wv >> 1, wc = wv & 1;
    const int m0 = blockIdx.y * 128;
    const int n0 = blockIdx.x * 128;
    const int lr = lane & 15;
    const int lk = (lane >> 4) * 8;
    const int srow = t >> 2;             // staging row (and +64)
    const int skc = (t & 3) * 8;         // staging k-col (8 elements)

    f32x4 acc[4][4] = {};
    s16x8 ra0, ra1;
    float4 rb00, rb01, rb10, rb11;

#define LOADG(k0)                                                                        \
    {                                                                                    \
        ra0 = *reinterpret_cast<const s16x8*>(&A[(size_t)(m0 + srow) * DD + (k0) + skc]);       \
        ra1 = *reinterpret_cast<const s16x8*>(&A[(size_t)(m0 + 64 + srow) * DD + (k0) + skc]);  \
        rb00 = *reinterpret_cast<const float4*>(&Bf[(size_t)(n0 + srow) * DD + (k0) + skc]);    \
        rb01 = *reinterpret_cast<const float4*>(&Bf[(size_t)(n0 + srow) * DD + (k0) + skc + 4]);\
        rb10 = *reinterpret_cast<const float4*>(&Bf[(size_t)(n0 + 64 + srow) * DD + (k0) + skc]);    \
        rb11 = *reinterpret_cast<const float4*>(&Bf[(size_t)(n0 + 64 + srow) * DD + (k0) + skc + 4]);\
    }
#define WRITEL(buf)                                                         \
    {                                                                       \
        *reinterpret_cast<s16x8*>(&As[buf][srow][skc]) = ra0;               \
        *reinterpret_cast<s16x8*>(&As[buf][srow + 64][skc]) = ra1;          \
        *reinterpret_cast<s16x8*>(&Bs[buf][srow][skc]) = cvt8(rb00, rb01);  \
        *reinterpret_cast<s16x8*>(&Bs[buf][srow + 64][skc]) = cvt8(rb10, rb11); \
    }

    LOADG(0)
    WRITEL(0)
    __syncthreads();
    LOADG(BK)                            // tile 1 in regs

#pragma unroll
    for (int k = 0; k < 8; ++k) {
        const int cur = k & 1;
        if (k < 7) WRITEL(cur ^ 1)       // write tile k+1 (regs loaded an iter ago)
        s16x8 a[4], b[4];
#pragma unroll
        for (int i = 0; i < 4; ++i)
            a[i] = *reinterpret_cast<const s16x8*>(&As[cur][wr * 64 + i * 16 + lr][lk]);
#pragma unroll
        for (int j = 0; j < 4; ++j)
            b[j] = *reinterpret_cast<const s16x8*>(&Bs[cur][wc * 64 + j * 16 + lr][lk]);
        if (k < 6) LOADG((k + 2) * BK)   // issue loads 2 tiles ahead
#pragma unroll
        for (int i = 0; i < 4; ++i)
#pragma unroll
            for (int j = 0; j < 4; ++j)
                acc[i][j] = __builtin_amdgcn_mfma_f32_16x16x32_bf16(
                    a[i], b[j], acc[i][j], 0, 0, 0);
        __syncthreads();                 // all reads of buf[cur] done; writes visible
    }
#undef LOADG
#undef WRITEL

    // C/D layout: col = lane&15, row = (lane>>4)*4 + reg
    const int crow = (lane >> 4) * 4;
    const int ccol = lane & 15;
#pragma unroll
    for (int i = 0; i < 4; ++i)
#pragma unroll
        for (int j = 0; j < 4; ++j)
#pragma unroll
            for (int r = 0; r < 4; ++r)
                C[(size_t)(m0 + wr * 64 + i * 16 + crow + r) * NOUT
                  + n0 + wc * 64 + j * 16 + ccol] = acc[i][j][r];
}

extern "C" void kernel_launch(void* const* d_in, const int* in_sizes, int n_in,
                              void* d_out, int out_size, void* d_ws, size_t ws_size,
                              hipStream_t stream) {
    const float* x  = (const float*)d_in[0];
    const float* lw = (const float*)d_in[1];   // [H][D][D] == [2048][256] row-major
    const int*   ei = (const int*)d_in[4];     // int32 delivery (confirmed R8-R11)
    float* out = (float*)d_out;

    short* aggb = (short*)d_ws;                // 2 MB bf16

    scan_agg_k<<<NBA, 1024, 0, stream>>>(x, ei, ei + EE, aggb);

    dim3 ggrid(NOUT / 128, NN / 128);          // (16, 32) = 512 blocks
    gemm_k<<<ggrid, 256, 0, stream>>>(aggb, lw, out);
}

// Round 13
// 42.299 us; speedup vs baseline: 2.3850x; 1.0301x over previous
//
#include <hip/hip_runtime.h>
#include <hip/hip_bf16.h>

// GATLayer, scalar attention => uniform 1/deg over DISTINCT neighbors.
//   out[n, h*D+d] = sum_k W[h,d,k] * agg_x[n,k]
//   agg_x[n,:]    = mean_{j in distinct nbr(n)} x[j,:]  (mean over all N if deg==0)
// 2 launches:
//   scan_agg_k : 1024-thr blockwise edge scan, per-block STAGGERED start
//                (defeats lockstep same-line L2 contention) -> LDS bitmask ->
//                shfl-prefix compaction -> 8-deep gather-mean
//   gemm_k     : reg-staged MFMA GEMM, W fp32->bf16 converted during staging

constexpr int NN = 4096;          // nodes
constexpr int DD = 256;           // channels
constexpr int EE = 131072;        // edges
constexpr int MW = NN / 32;       // 128 mask words per row
constexpr int NOUT = 2048;        // H*D
constexpr int RPB = 16;           // rows per scan block (16 waves, 1 row/wave)
constexpr int NBA = NN / RPB;     // 256 blocks
constexpr int LCAP = 128;         // neighbor cap (deg ~ Poisson(32), max ~70)
constexpr int BK = 32;
constexpr int PADK = 40;          // 80B LDS row stride (proven R8)
constexpr int NU4 = EE / 4;       // 32768 int4 u-words (pow2)

typedef __attribute__((ext_vector_type(4))) float f32x4;
typedef __attribute__((ext_vector_type(8))) short s16x8;

__device__ inline short f2bf(float f) {
    __hip_bfloat16 h = __float2bfloat16(f);
    return *reinterpret_cast<short*>(&h);
}
__device__ inline s16x8 cvt8(const float4& a, const float4& b) {
    s16x8 o;
    o[0] = f2bf(a.x); o[1] = f2bf(a.y); o[2] = f2bf(a.z); o[3] = f2bf(a.w);
    o[4] = f2bf(b.x); o[5] = f2bf(b.y); o[6] = f2bf(b.z); o[7] = f2bf(b.w);
    return o;
}

// ---- launch 1: staggered edge scan -> LDS bitmask -> compaction -> gather ----
__global__ __launch_bounds__(1024) void scan_agg_k(
        const float* __restrict__ x, const int* __restrict__ eu,
        const int* __restrict__ ev, short* __restrict__ aggb) {
    __shared__ unsigned int bm[RPB][MW];     // 8 KB private bitmask
    __shared__ int nbr[RPB][LCAP];           // 8 KB
    __shared__ int cnt[RPB];
    const int t = threadIdx.x;
    const int row0 = blockIdx.x * RPB;
    const int rot = (blockIdx.x * 128) & (NU4 - 1);   // 2 KB stagger per block

    for (int i = t; i < RPB * MW; i += 1024) ((unsigned int*)bm)[i] = 0u;
    __syncthreads();

    // scan: 32768 int4 u-loads, 32/thread in 4 rounds of 8-in-flight,
    // block-staggered so concurrent blocks hit different L2 channels
    const int4* eu4 = reinterpret_cast<const int4*>(eu);
    for (int r0 = 0; r0 < 4; ++r0) {
        int idxs[8];
        int4 u4[8];
#pragma unroll
        for (int j = 0; j < 8; ++j)
            idxs[j] = (t + (r0 * 8 + j) * 1024 + rot) & (NU4 - 1);
#pragma unroll
        for (int j = 0; j < 8; ++j)
            u4[j] = eu4[idxs[j]];
#pragma unroll
        for (int j = 0; j < 8; ++j) {
            const int base = idxs[j] * 4;
            const int us[4] = {u4[j].x, u4[j].y, u4[j].z, u4[j].w};
#pragma unroll
            for (int q = 0; q < 4; ++q)
                if ((unsigned)(us[q] - row0) < (unsigned)RPB) {
                    int v = ev[base + q];
                    atomicOr(&bm[us[q] - row0][v >> 5], 1u << (v & 31));
                }
        }
    }
    __syncthreads();

    const int r = t >> 6;                    // 16 waves, one row per wave
    const int lane = t & 63;
    {                                        // compaction: shfl prefix, no atomics
        unsigned int w0 = bm[r][lane * 2];
        unsigned int w1 = bm[r][lane * 2 + 1];
        int c = __popc(w0) + __popc(w1);
        int pre = c;
#pragma unroll
        for (int d = 1; d < 64; d <<= 1) {   // inclusive scan over 64 lanes
            int y = __shfl_up(pre, d);
            if (lane >= d) pre += y;
        }
        if (lane == 63) cnt[r] = pre;        // total distinct neighbors
        pre -= c;                            // exclusive prefix
        int idx = pre;
        while (w0) {
            int b = __ffs(w0) - 1; w0 &= w0 - 1;
            if (idx < LCAP) nbr[r][idx] = lane * 64 + b;
            ++idx;
        }
        while (w1) {
            int b = __ffs(w1) - 1; w1 &= w1 - 1;
            if (idx < LCAP) nbr[r][idx] = lane * 64 + 32 + b;
            ++idx;
        }
    }
    __syncthreads();

    const int c4 = lane << 2;                // 4 ch/lane -> 64 lanes = full row
    {
        const int deg = min(cnt[r], LCAP);
        float4 acc = make_float4(0.f, 0.f, 0.f, 0.f);
        for (int q0 = 0; q0 < deg; q0 += 8) {        // 8 gathers in flight
            int nn[8];
            float4 v[8];
#pragma unroll
            for (int j = 0; j < 8; ++j)
                nn[j] = nbr[r][(q0 + j < deg) ? q0 + j : q0];
#pragma unroll
            for (int j = 0; j < 8; ++j)
                v[j] = *reinterpret_cast<const float4*>(&x[(size_t)nn[j] * DD + c4]);
#pragma unroll
            for (int j = 0; j < 8; ++j)
                if (q0 + j < deg) {
                    acc.x += v[j].x; acc.y += v[j].y;
                    acc.z += v[j].z; acc.w += v[j].w;
                }
        }
        float inv;
        if (deg > 0) {
            inv = 1.f / (float)deg;
        } else {                 // exact fallback: mean over all N (never expected)
            acc = make_float4(0.f, 0.f, 0.f, 0.f);
            for (int n = 0; n < NN; ++n) {
                float4 v = *reinterpret_cast<const float4*>(&x[(size_t)n * DD + c4]);
                acc.x += v.x; acc.y += v.y; acc.z += v.z; acc.w += v.w;
            }
            inv = 1.f / (float)NN;
        }
        short4 o;
        o.x = f2bf(acc.x * inv); o.y = f2bf(acc.y * inv);
        o.z = f2bf(acc.z * inv); o.w = f2bf(acc.w * inv);
        *reinterpret_cast<short4*>(&aggb[(size_t)(row0 + r) * DD + c4]) = o;
    }
}

// ---- launch 2: MFMA GEMM  C[4096][2048] = aggb[4096][256] * W[2048][256]^T ----
// 128x128 tile, BK=32, padded double-buffered LDS, reg-staged (write-early,
// load-2-ahead), one barrier per K-step. W converted fp32->bf16 in staging.
__global__ __launch_bounds__(256, 2) void gemm_k(
        const short* __restrict__ A, const float* __restrict__ Bf,
        float* __restrict__ C) {
    __shared__ short As[2][128][PADK];   // 2 x 10 KB
    __shared__ short Bs[2][128][PADK];   // 2 x 10 KB
    const int t = threadIdx.x;
    const int lane = t & 63;
    const int wv = t >> 6;
    const int wr = wv >> 1, wc = wv & 1;
    const int m0 = blockIdx.y * 128;
    const int n0 = blockIdx.x * 128;
    const int lr = lane & 15;
    const int lk = (lane >> 4) * 8;
    const int srow = t >> 2;             // staging row (and +64)
    const int skc = (t & 3) * 8;         // staging k-col (8 elements)

    f32x4 acc[4][4] = {};
    s16x8 ra0, ra1;
    float4 rb00, rb01, rb10, rb11;

#define LOADG(k0)                                                                        \
    {                                                                                    \
        ra0 = *reinterpret_cast<const s16x8*>(&A[(size_t)(m0 + srow) * DD + (k0) + skc]);       \
        ra1 = *reinterpret_cast<const s16x8*>(&A[(size_t)(m0 + 64 + srow) * DD + (k0) + skc]);  \
        rb00 = *reinterpret_cast<const float4*>(&Bf[(size_t)(n0 + srow) * DD + (k0) + skc]);    \
        rb01 = *reinterpret_cast<const float4*>(&Bf[(size_t)(n0 + srow) * DD + (k0) + skc + 4]);\
        rb10 = *reinterpret_cast<const float4*>(&Bf[(size_t)(n0 + 64 + srow) * DD + (k0) + skc]);    \
        rb11 = *reinterpret_cast<const float4*>(&Bf[(size_t)(n0 + 64 + srow) * DD + (k0) + skc + 4]);\
    }
#define WRITEL(buf)                                                         \
    {                                                                       \
        *reinterpret_cast<s16x8*>(&As[buf][srow][skc]) = ra0;               \
        *reinterpret_cast<s16x8*>(&As[buf][srow + 64][skc]) = ra1;          \
        *reinterpret_cast<s16x8*>(&Bs[buf][srow][skc]) = cvt8(rb00, rb01);  \
        *reinterpret_cast<s16x8*>(&Bs[buf][srow + 64][skc]) = cvt8(rb10, rb11); \
    }

    LOADG(0)
    WRITEL(0)
    __syncthreads();
    LOADG(BK)                            // tile 1 in regs

#pragma unroll
    for (int k = 0; k < 8; ++k) {
        const int cur = k & 1;
        if (k < 7) WRITEL(cur ^ 1)       // write tile k+1 (regs loaded an iter ago)
        s16x8 a[4], b[4];
#pragma unroll
        for (int i = 0; i < 4; ++i)
            a[i] = *reinterpret_cast<const s16x8*>(&As[cur][wr * 64 + i * 16 + lr][lk]);
#pragma unroll
        for (int j = 0; j < 4; ++j)
            b[j] = *reinterpret_cast<const s16x8*>(&Bs[cur][wc * 64 + j * 16 + lr][lk]);
        if (k < 6) LOADG((k + 2) * BK)   // issue loads 2 tiles ahead
#pragma unroll
        for (int i = 0; i < 4; ++i)
#pragma unroll
            for (int j = 0; j < 4; ++j)
                acc[i][j] = __builtin_amdgcn_mfma_f32_16x16x32_bf16(
                    a[i], b[j], acc[i][j], 0, 0, 0);
        __syncthreads();                 // all reads of buf[cur] done; writes visible
    }
#undef LOADG
#undef WRITEL

    // C/D layout: col = lane&15, row = (lane>>4)*4 + reg
    const int crow = (lane >> 4) * 4;
    const int ccol = lane & 15;
#pragma unroll
    for (int i = 0; i < 4; ++i)
#pragma unroll
        for (int j = 0; j < 4; ++j)
#pragma unroll
            for (int r = 0; r < 4; ++r)
                C[(size_t)(m0 + wr * 64 + i * 16 + crow + r) * NOUT
                  + n0 + wc * 64 + j * 16 + ccol] = acc[i][j][r];
}

extern "C" void kernel_launch(void* const* d_in, const int* in_sizes, int n_in,
                              void* d_out, int out_size, void* d_ws, size_t ws_size,
                              hipStream_t stream) {
    const float* x  = (const float*)d_in[0];
    const float* lw = (const float*)d_in[1];   // [H][D][D] == [2048][256] row-major
    const int*   ei = (const int*)d_in[4];     // int32 delivery (confirmed R8-R12)
    float* out = (float*)d_out;

    short* aggb = (short*)d_ws;                // 2 MB bf16

    scan_agg_k<<<NBA, 1024, 0, stream>>>(x, ei, ei + EE, aggb);

    dim3 ggrid(NOUT / 128, NN / 128);          // (16, 32) = 512 blocks
    gemm_k<<<ggrid, 256, 0, stream>>>(aggb, lw, out);
}